// Round 1
// baseline (168.299 us; speedup 1.0000x reference)
//
#include <hip/hip_runtime.h>
#include <hip/hip_fp16.h>
#include <math.h>

#define W 1024
#define H 768
#define PIX (W*H)          // 786432
#define NIMG 4
#define SNUM 131072
#define SEG 3072           // pixels per compaction segment (one block's span)
#define NSEG 256           // segments per image
#define NBLK (NIMG*NSEG)   // 1024 blocks for prep/compact
#define MASKV (-1e-8f)

__device__ __forceinline__ void sobel_g(const float* __restrict__ img, int y, int x,
                                        float& gx, float& gy) {
    const float* r0 = img + (y - 1) * W + x;
    const float* r1 = r0 + W;
    const float* r2 = r1 + W;
    float a00 = r0[-1], a01 = r0[0], a02 = r0[1];
    float a10 = r1[-1],              a12 = r1[1];
    float a20 = r2[-1], a21 = r2[0], a22 = r2[1];
    gx = (a02 - a00) + 2.f * (a12 - a10) + (a22 - a20);
    gy = (a00 - a20) + 2.f * (a01 - a21) + (a02 - a22);
}

// ---- D0: sobel magnitude max + valid count per 3072-px block + pack {inp,tgt} fp16 ----
__global__ __launch_bounds__(256) void prep_kernel(const float* __restrict__ inputs,
                                                   const float* __restrict__ targets,
                                                   const float* __restrict__ images,
                                                   __half2* __restrict__ pairIT,
                                                   float* __restrict__ blockmaxB,
                                                   int* __restrict__ blkVB) {
    int b = blockIdx.x, t = threadIdx.x;
    int i = b >> 8, bb = b & 255;
    const float* img = images + (size_t)i * 3 * PIX;   // channel 0
    const float* inp = inputs + (size_t)i * PIX;
    const float* tgt = targets + (size_t)i * PIX;
    __half2* pIT = pairIT + (size_t)i * PIX;

    float mx = 0.f; int vc = 0;
#pragma unroll
    for (int k = 0; k < 12; k++) {
        int gp = bb * SEG + k * 256 + t;
        int y = gp >> 10, x = gp & (W - 1);
        float e = 0.f;
        if (y >= 1 && y <= H - 2 && x >= 1 && x <= W - 2) {
            float gx, gy;
            sobel_g(img, y, x, gx, gy);
            e = sqrtf(gx * gx + gy * gy);
        }
        mx = fmaxf(mx, e);
        float inv = inp[gp], tgv = tgt[gp];
        __half2 h;
        h.x = __float2half_rn(inv);
        h.y = __float2half_rn(tgv);
        pIT[gp] = h;
        vc += (tgv > MASKV) ? 1 : 0;
    }
    // wave reduce (max, sum) then cross-wave via 4-slot LDS
    for (int o = 32; o; o >>= 1) {
        mx = fmaxf(mx, __shfl_down(mx, o));
        vc += __shfl_down(vc, o);
    }
    __shared__ float sm[4];
    __shared__ int sv[4];
    int lane = t & 63, w = t >> 6;
    if (lane == 0) { sm[w] = mx; sv[w] = vc; }
    __syncthreads();
    if (t == 0) {
        blockmaxB[b] = fmaxf(fmaxf(sm[0], sm[1]), fmaxf(sm[2], sm[3]));
        blkVB[b] = sv[0] + sv[1] + sv[2] + sv[3];
    }
}

// ---- D1: thr/vtot from 256-entry arrays + segmented compaction (1 sync/unit) ----
__global__ __launch_bounds__(256) void compact_kernel(const float* __restrict__ images,
                                                      const float* __restrict__ targets,
                                                      const float* __restrict__ blockmaxB,
                                                      const int* __restrict__ blkVB,
                                                      float2* __restrict__ anchorSeg,
                                                      int* __restrict__ compVSeg,
                                                      int* __restrict__ cntEB,
                                                      int* __restrict__ cntVB,
                                                      int* __restrict__ vtotG) {
    int b = blockIdx.x, t = threadIdx.x;
    int i = b >> 8, bb = b & 255;
    int lane = t & 63, w = t >> 6;
    unsigned long long lm = (1ull << lane) - 1ull;
    const float* img = images + (size_t)i * 3 * PIX;

    // redundant per-image reduce over 256 entries (1KB, L2-hot)
    __shared__ float sR[256];
    __shared__ int sI[256];
    sR[t] = blockmaxB[(i << 8) + t];
    sI[t] = blkVB[(i << 8) + t];
    __syncthreads();
    for (int o = 128; o; o >>= 1) {
        if (t < o) { sR[t] = fmaxf(sR[t], sR[t + o]); sI[t] += sI[t + o]; }
        __syncthreads();
    }
    float thr = 0.1f * sR[0];
    int vtot = sI[0];
    if (bb == 0 && t == 0) vtotG[i] = vtot;

    // edge compaction into this block's 3072-wide segment, pixel order preserved.
    // double-buffered wave-count slots -> exactly one barrier per unit.
    __shared__ int sW2[2][4];
    int baseE = 0;
    float2* aSeg = anchorSeg + (size_t)i * PIX + (size_t)bb * SEG;
    for (int k = 0; k < 12; k++) {
        int gp = bb * SEG + k * 256 + t;
        int y = gp >> 10, x = gp & (W - 1);
        float e = 0.f, gx = 0.f, gy = 0.f;
        bool inner = (y >= 1 && y <= H - 2 && x >= 1 && x <= W - 2);
        if (inner) { sobel_g(img, y, x, gx, gy); e = sqrtf(gx * gx + gy * gy); }
        bool isE = (e >= thr);                 // border e=0: matches padded ref
        unsigned long long mE = __ballot(isE);
        int* sw = sW2[k & 1];
        if (lane == 0) sw[w] = __popcll(mE);
        __syncthreads();
        int base = baseE;
        for (int q = 0; q < w; q++) base += sw[q];
        if (isE) {
            float th = inner ? atan2f(gy, gx) : 0.f;
            aSeg[base + __popcll(mE & lm)] = make_float2(__int_as_float(gp), th);
        }
        baseE += sw[0] + sw[1] + sw[2] + sw[3];
    }
    if (t == 0) cntEB[(i << 8) + bb] = baseE;

    if (vtot < PIX) {                          // general path only: segmented compV
        const float* tgt = targets + (size_t)i * PIX;
        int* vSeg = compVSeg + (size_t)i * PIX + (size_t)bb * SEG;
        int baseV = 0;
        for (int k = 0; k < 12; k++) {
            int gp = bb * SEG + k * 256 + t;
            bool v = tgt[gp] > MASKV;
            unsigned long long mV = __ballot(v);
            int* sw = sW2[k & 1];
            if (k == 0) __syncthreads();       // order vs edge loop's last readers of sW2[0]... (k=1 buffer differs; k=0 needs the fence)
            if (lane == 0) sw[w] = __popcll(mV);
            __syncthreads();
            int base = baseV;
            for (int q = 0; q < w; q++) base += sw[q];
            if (v) vSeg[base + __popcll(mV & lm)] = gp;
            baseV += sw[0] + sw[1] + sw[2] + sw[3];
        }
        if (t == 0) cntVB[(i << 8) + bb] = baseV;
    }
}

// ---- D2: loss (fp16 gathers, XCD-affine: image = blockIdx & 3 -> XCDs {i, i+4}) ----
__device__ __forceinline__ void pair_term(float2 a, float2 b, float& eqs, float& uns) {
    float cm = ((a.y > MASKV) ? 1.f : 0.f) * ((b.y > MASKV) ? 1.f : 0.f);
    float ratio = (a.y + 1e-6f) / (b.y + 1e-6f);
    const float HIv = 1.03f;
    const float LOv = (float)(1.0 / 1.03);
    bool eq = (ratio < HIv) && (ratio > LOv);
    if (eq) {
        float d = a.x - b.x;
        eqs += d * d * cm;
    } else {
        float label = ((ratio >= HIv) ? 1.f : 0.f) + ((ratio <= LOv) ? -1.f : 0.f);
        uns += log1pf(expf((b.x - a.x) * label)) * cm;
    }
}

__device__ __forceinline__ float2 h2f(__half2 h) {
    return make_float2(__half2float(h.x), __half2float(h.y));
}

__global__ __launch_bounds__(256) void loss_kernel(const __half2* __restrict__ pairIT,
                                                   const float2* __restrict__ anchorSeg,
                                                   const int* __restrict__ compVSeg,
                                                   const int* __restrict__ cntEB,
                                                   const int* __restrict__ cntVB,
                                                   const int* __restrict__ vtotG,
                                                   const int* __restrict__ ra,
                                                   const int* __restrict__ rd,
                                                   const int* __restrict__ rp,
                                                   float2* __restrict__ partials) {
    int b = blockIdx.x, t = threadIdx.x;
    // XCD affinity: block b -> XCD b%8; image = b&3 pins image i to XCDs {i, i+4}.
    // fp16 slice (3.15MB) fits each 4MB XCD L2. Wrong mapping => perf-neutral only.
    int i = b & 3;
    int sub = b >> 2;                          // [0, 512) within image

    __shared__ int sT[256];
    __shared__ int SE[256];
    __shared__ int SV[256];
    __shared__ int sTot[1];

    // 256-entry exclusive scan of per-segment edge counts (1KB load, 8 rounds)
    int c = cntEB[(i << 8) + t];
    sT[t] = c;
    __syncthreads();
    for (int o = 1; o < 256; o <<= 1) {
        int v = (t >= o) ? sT[t - o] : 0;
        __syncthreads();
        sT[t] += v;
        __syncthreads();
    }
    SE[t] = sT[t] - c;
    if (t == 255) sTot[0] = sT[255];
    __syncthreads();
    int eT = sTot[0];                          // etot; >=1 always (emax passes thr)
    int vT = vtotG[i];
    bool needV = (vT > 0) && (vT < PIX);
    if (needV) {                               // block-uniform branch
        int cv = cntVB[(i << 8) + t];
        sT[t] = cv;
        __syncthreads();
        for (int o = 1; o < 256; o <<= 1) {
            int v = (t >= o) ? sT[t - o] : 0;
            __syncthreads();
            sT[t] += v;
            __syncthreads();
        }
        SV[t] = sT[t] - cv;
        __syncthreads();
    }
    int nval = (vT > 0) ? vT : 1;

    int s = sub * 256 + t;
    const __half2* pIT = pairIT + (size_t)i * PIX;

    int j = ra[(size_t)i * SNUM + s] % eT;
    int lo = 0;                                // largest seg with SE[seg] <= j (8 levels)
#pragma unroll
    for (int st = 128; st; st >>= 1) {
        int n = lo + st;                       // always <= 255 (lo is multiple of 2*st)
        if (SE[n] <= j) lo = n;
    }
    float2 ac = anchorSeg[(size_t)i * PIX + (size_t)lo * SEG + (j - SE[lo])];
    int anchor = __float_as_int(ac.x);
    float sv, cv;
    __sincosf(ac.y, &sv, &cv);
    int row_a = anchor >> 10, col_a = anchor & (W - 1);

    int pix4[4];
#pragma unroll
    for (int k = 0; k < 4; k++) {
        int r = rd[((size_t)i * 4 + k) * SNUM + s];
        float dist = ((float)r + 2.0f) * ((k < 2) ? -1.f : 1.f);
        int cc = col_a + (int)rintf(dist * cv);  // round-half-even = jnp.round
        int rr = row_a + (int)rintf(dist * sv);
        cc = min(max(cc, 0), W - 1);
        rr = min(max(rr, 0), H - 1);
        pix4[k] = (rr << 10) | cc;
    }
    int2 rr2 = *(const int2*)(rp + (size_t)i * 2 * SNUM + 2 * s);
    int r0 = rr2.x % nval, r1 = rr2.y % nval;
    int A, B;
    if (!needV) {                              // identity compaction cases
        A = r0; B = r1;
    } else {
        int lo2 = 0, lo3 = 0;
#pragma unroll
        for (int st = 128; st; st >>= 1) {
            int n2 = lo2 + st;
            if (SV[n2] <= r0) lo2 = n2;
            int n3 = lo3 + st;
            if (SV[n3] <= r1) lo3 = n3;
        }
        A = compVSeg[(size_t)i * PIX + (size_t)lo2 * SEG + (r0 - SV[lo2])];
        B = compVSeg[(size_t)i * PIX + (size_t)lo3 * SEG + (r1 - SV[lo3])];
    }

    float2 a0 = h2f(pIT[pix4[0]]), a1 = h2f(pIT[pix4[1]]);
    float2 a2 = h2f(pIT[pix4[2]]), a3 = h2f(pIT[pix4[3]]);
    float2 b0 = h2f(pIT[A]), b1 = h2f(pIT[B]);
    float eqs = 0.f, uns = 0.f;
    pair_term(a0, a1, eqs, uns);
    pair_term(a1, a2, eqs, uns);
    pair_term(a2, a3, eqs, uns);
    pair_term(b0, b1, eqs, uns);

    // shfl reduce + 4-slot LDS
    for (int o = 32; o; o >>= 1) {
        eqs += __shfl_down(eqs, o);
        uns += __shfl_down(uns, o);
    }
    __shared__ float sE4[4], sU4[4];
    int lane = t & 63, w = t >> 6;
    if (lane == 0) { sE4[w] = eqs; sU4[w] = uns; }
    __syncthreads();
    if (t == 0)
        partials[b] = make_float2(sE4[0] + sE4[1] + sE4[2] + sE4[3],
                                  sU4[0] + sU4[1] + sU4[2] + sU4[3]);
}

// ---- D3: final reduce ----
__global__ __launch_bounds__(256) void final_kernel(const float2* __restrict__ partials,
                                                    float* __restrict__ out) {
    int t = threadIdx.x;                       // 256 threads, 2048 partials
    double acc = 0.0;
#pragma unroll
    for (int k = 0; k < 8; k++) {
        float2 p = partials[t + k * 256];
        acc += (double)p.x + (double)p.y;
    }
    __shared__ double sm[256];
    sm[t] = acc;
    __syncthreads();
    for (int o = 128; o > 0; o >>= 1) {
        if (t < o) sm[t] += sm[t + o];
        __syncthreads();
    }
    if (t == 0) {
        double denom = 4.0 * (double)SNUM;     // each mean over 4*S terms; ALPHA=1
        out[0] = (float)(sm[0] / denom / (double)NIMG);
    }
}

extern "C" void kernel_launch(void* const* d_in, const int* in_sizes, int n_in,
                              void* d_out, int out_size, void* d_ws, size_t ws_size,
                              hipStream_t stream) {
    const float* inputs  = (const float*)d_in[0];
    const float* targets = (const float*)d_in[1];
    const float* images  = (const float*)d_in[2];
    const int* ra = (const int*)d_in[3];
    const int* rd = (const int*)d_in[4];
    const int* rp = (const int*)d_in[5];
    float* out = (float*)d_out;

    char* ws = (char*)d_ws;
    int*      vtotG     = (int*)ws;                        // [4]
    float*    blockmaxB = (float*)(ws + 1024);             // [1024] = 4KB
    int*      blkVB     = (int*)(ws + 8192);               // [1024] = 4KB
    int*      cntEB     = (int*)(ws + 16384);              // [1024] = 4KB
    int*      cntVB     = (int*)(ws + 24576);              // [1024] = 4KB
    float2*   partials  = (float2*)(ws + 32768);           // [2048] = 16KB
    __half2*  pairIT    = (__half2*)(ws + 1048576);        // 12.6MB (fp16 packed)
    float2*   anchorSeg = (float2*)(ws + 14680064);        // 25.2MB (3072-segmented)
    int*      compVSeg  = (int*)(ws + 39845888);           // 12.6MB (3072-segmented)
    // total ~53MB; compVSeg/cntVB written+read only when vtot<PIX

    prep_kernel<<<NBLK, 256, 0, stream>>>(inputs, targets, images,
                                          pairIT, blockmaxB, blkVB);
    compact_kernel<<<NBLK, 256, 0, stream>>>(images, targets, blockmaxB, blkVB,
                                             anchorSeg, compVSeg, cntEB, cntVB, vtotG);
    loss_kernel<<<2048, 256, 0, stream>>>(pairIT, anchorSeg, compVSeg,
                                          cntEB, cntVB, vtotG,
                                          ra, rd, rp, partials);
    final_kernel<<<1, 256, 0, stream>>>(partials, out);
}